// Round 6
// baseline (1134.192 us; speedup 1.0000x reference)
//
#include <hip/hip_runtime.h>
#include <hip/hip_bf16.h>
#include <cstdint>
#include <cstddef>

// ---------------- problem constants ----------------
static constexpr int Bv  = 32;
static constexpr int Cv  = 384;
static constexpr int Nv  = 49;    // tokens per window
static constexpr int Mv  = 32 * 64 * 49;   // 100352 token-rows
static constexpr float SCALEv = 0.17677669529663687f;  // 32^-0.5

using bf16 = __hip_bfloat16;
typedef __bf16 bf16x8 __attribute__((ext_vector_type(8)));
typedef float  f32x4  __attribute__((ext_vector_type(4)));

// ---------------- weight transpose + bf16 cast: wt[n*K+k] = w[k*N+n] ----------------
__global__ __launch_bounds__(256)
void wt_kernel(const float* __restrict__ w, bf16* __restrict__ wt, int K, int N) {
    int idx = blockIdx.x * 256 + threadIdx.x;
    if (idx >= K * N) return;
    int n = idx / K, k = idx - n * K;
    wt[idx] = (bf16)w[(size_t)k * N + n];
}

// ---------------- combined rel-bias + shift-mask table (TRANSPOSED: [q][k]) --------
// BMt[cls][h][q 64][k 64] f32.  cls = (hb==7)*2 + (wb==7).
// k >= 49 -> -1e30 (kills padded K columns in swapped-QK^T layout); q clamped to 48.
__global__ __launch_bounds__(256)
void bm_kernel(const float* __restrict__ btab, float* __restrict__ bmt) {
    const int cls = blockIdx.x, h = blockIdx.y;
    for (int idx = threadIdx.x; idx < 4096; idx += 256) {
        int q = idx >> 6, k = idx & 63;
        float v;
        if (k >= 49) {
            v = -1e30f;
        } else {
            int n = q < 49 ? q : 48;   // query token
            int m = k;                 // key token
            int i1 = n / 7, j1 = n - i1 * 7;
            int i2 = m / 7, j2 = m - i2 * 7;
            v = btab[((i1 - i2 + 6) * 13 + (j1 - j2 + 6)) * 12 + h];
            int lh1 = (cls & 2) ? (i1 < 4 ? 1 : 2) : 0;
            int lw1 = (cls & 1) ? (j1 < 4 ? 1 : 2) : 0;
            int lh2 = (cls & 2) ? (i2 < 4 ? 1 : 2) : 0;
            int lw2 = (cls & 1) ? (j2 < 4 ? 1 : 2) : 0;
            if ((lh1 * 3 + lw1) != (lh2 * 3 + lw2)) v += -100.f;
        }
        bmt[((size_t)(cls * 12 + h) * 64 + q) * 64 + k] = v;
    }
}

// ---------------- LayerNorm (one wave per 384-ch row) ----------------
template <int MODE>
__global__ __launch_bounds__(256)
void ln_kernel(const float* __restrict__ src, const float* __restrict__ gam,
               const float* __restrict__ bet, bf16* __restrict__ dst) {
    const int wave = threadIdx.x >> 6, lane = threadIdx.x & 63;
    const int r = blockIdx.x * 4 + wave;             // output row
    size_t srow;
    if (MODE == 0) {
        int w  = r / 49, n = r - w * 49;
        int b  = w >> 6, win = w & 63;
        int hb = win >> 3, wb = win & 7;
        int ii = n / 7, jj = n - ii * 7;
        int hh = hb * 7 + ii + 3; if (hh >= 56) hh -= 56;   // shifted -> source row
        int ww = wb * 7 + jj + 3; if (ww >= 56) ww -= 56;
        srow = (size_t)b * 3136 + hh * 56 + ww;
    } else {
        srow = (size_t)r;
    }
    const float* p = src + srow * 384;
    float vals[6];
    float s = 0.f, s2 = 0.f;
#pragma unroll
    for (int t = 0; t < 6; ++t) {
        float v = p[t * 64 + lane];
        vals[t] = v; s += v; s2 += v * v;
    }
#pragma unroll
    for (int o = 32; o > 0; o >>= 1) {
        s  += __shfl_xor(s,  o, 64);
        s2 += __shfl_xor(s2, o, 64);
    }
    const float mu  = s * (1.f / 384.f);
    const float var = s2 * (1.f / 384.f) - mu * mu;
    const float rs  = rsqrtf(var + 1e-5f);
    bf16* q = dst + (size_t)r * 384;
#pragma unroll
    for (int t = 0; t < 6; ++t) {
        int e = t * 64 + lane;
        q[e] = (bf16)((vals[t] - mu) * rs * gam[e] + bet[e]);
    }
}

// ---------------- MFMA windowed attention: one wave per (window, head) -------------
// SWAPPED QK^T (in-register softmax): acc[i][j] = mfma(K_i, Q_j) = S^T, so the
// D-layout puts q in lane l16 (col) and the 64 k-values in (i, quad, t): the
// row-softmax reduces 16 values IN-REGISTER + 2 shfl_xor (16,32) across quads —
// 16 cross-lane ops total instead of 128 4-step chains.  Bias table is [q][k]
// (k inner, -1e30 for k>=49 kills padded K; padded q rows discarded at store).
// P is normalized in f32 (1/sum folded in; q-index is lane-local so no
// redistribution), packed 4x bf16 = 8B per write into Ps[q][k].  PV step and
// epilogue layouts unchanged (epilogue drops the inv multiply).
__global__ __launch_bounds__(64)
void attn_kernel(const bf16* __restrict__ qkv, const float* __restrict__ bmt,
                 bf16* __restrict__ o) {
    const int w = blockIdx.x;          // 0..2047
    const int h = blockIdx.y;          // 0..11
    const int lane = threadIdx.x;
    const int quad = lane >> 4, l16 = lane & 15;
    __shared__ bf16 Vt[32][72];        // V^T, cols 49..63 zeroed
    __shared__ bf16 Ps[64][72];        // P[q][k], normalized, bf16

    const size_t rowbase = (size_t)w * 49;

    // stage V^T (coalesced global read, transposed LDS write)
    for (int idx = lane; idx < 49 * 16; idx += 64) {
        int row = idx >> 4, dp = (idx & 15) << 1;
        const bf16* src = qkv + (rowbase + row) * 1152 + 768 + h * 32 + dp;
        Vt[dp][row]     = src[0];
        Vt[dp + 1][row] = src[1];
    }
    for (int idx = lane; idx < 512; idx += 64) {     // zero cols 49..63
        int d = idx >> 4, c = idx & 15;
        if (c) Vt[d][48 + c] = (bf16)0.f;
    }

    // ---- S^T = K Q^T : fragments straight from global (contiguous in k) ----
    f32x4 acc[4][4] = {};
    bf16x8 kf[4], qf[4];
#pragma unroll
    for (int i = 0; i < 4; ++i) {
        int row = 16 * i + l16; if (row > 48) row = 48;
        kf[i] = *(const bf16x8*)(qkv + (rowbase + row) * 1152 + 384 + h * 32 + quad * 8);
    }
#pragma unroll
    for (int j = 0; j < 4; ++j) {
        int row = 16 * j + l16; if (row > 48) row = 48;
        qf[j] = *(const bf16x8*)(qkv + (rowbase + row) * 1152 + h * 32 + quad * 8);
    }
#pragma unroll
    for (int i = 0; i < 4; ++i)
#pragma unroll
        for (int j = 0; j < 4; ++j)
            acc[i][j] = __builtin_amdgcn_mfma_f32_16x16x32_bf16(kf[i], qf[j], acc[i][j], 0, 0, 0);
    // acc[i][j][t] = S^T[k = 16i + 4*quad + t][q = 16j + l16]

    // ---- bias + in-register softmax per q (j, l16), write normalized P ----
    const int cls = (((w & 63) >= 56) ? 2 : 0) + (((w & 7) == 7) ? 1 : 0);
    const float* bmbase = bmt + (size_t)(cls * 12 + h) * 4096;
#pragma unroll
    for (int j = 0; j < 4; ++j) {
        f32x4 bm[4];
#pragma unroll
        for (int i = 0; i < 4; ++i)
            bm[i] = *(const f32x4*)(bmbase + (16 * j + l16) * 64 + 16 * i + quad * 4);
        float s[4][4];
        float mx = -3.0e38f;
#pragma unroll
        for (int i = 0; i < 4; ++i)
#pragma unroll
            for (int t = 0; t < 4; ++t) {
                s[i][t] = acc[i][j][t] + bm[i][t];
                mx = fmaxf(mx, s[i][t]);
            }
        mx = fmaxf(mx, __shfl_xor(mx, 16, 64));
        mx = fmaxf(mx, __shfl_xor(mx, 32, 64));
        float p[4][4];
        float sum = 0.f;
#pragma unroll
        for (int i = 0; i < 4; ++i)
#pragma unroll
            for (int t = 0; t < 4; ++t) {
                p[i][t] = __expf(s[i][t] - mx);
                sum += p[i][t];
            }
        sum += __shfl_xor(sum, 16, 64);
        sum += __shfl_xor(sum, 32, 64);
        const float inv = 1.f / sum;
#pragma unroll
        for (int i = 0; i < 4; ++i) {
            bf16 pk[4];
#pragma unroll
            for (int t = 0; t < 4; ++t) pk[t] = (bf16)(p[i][t] * inv);
            *(uint64_t*)(&Ps[16 * j + l16][16 * i + 4 * quad]) = *(const uint64_t*)pk;
        }
    }
    __syncthreads();

    // ---- O = P V ----
    f32x4 oacc[4][2] = {};
    bf16x8 vb[2][2];
#pragma unroll
    for (int jn = 0; jn < 2; ++jn)
#pragma unroll
        for (int ks = 0; ks < 2; ++ks)
            vb[jn][ks] = *(const bf16x8*)(&Vt[16 * jn + l16][32 * ks + quad * 8]);
#pragma unroll
    for (int i = 0; i < 4; ++i) {
#pragma unroll
        for (int ks = 0; ks < 2; ++ks) {
            bf16x8 pa = *(const bf16x8*)(&Ps[16 * i + l16][32 * ks + quad * 8]);
#pragma unroll
            for (int jn = 0; jn < 2; ++jn)
                oacc[i][jn] = __builtin_amdgcn_mfma_f32_16x16x32_bf16(pa, vb[jn][ks], oacc[i][jn], 0, 0, 0);
        }
    }

    // ---- store valid rows (P already normalized) ----
#pragma unroll
    for (int i = 0; i < 4; ++i) {
        int nbase = 16 * i + quad * 4;
#pragma unroll
        for (int t = 0; t < 4; ++t) {
            int n = nbase + t;
            if (n < 49) {
                bf16* dst = o + (rowbase + n) * 384 + h * 32;
                dst[l16]      = (bf16)(oacc[i][0][t]);
                dst[16 + l16] = (bf16)(oacc[i][1][t]);
            }
        }
    }
}

// ---------------- bf16 MFMA GEMM, C = A[M,K] @ Bt[N,K]^T ---------------------------
// REG-PREFETCH single-buffer structure (T14):
//   - LDS halved to 32 KB (single As/Bs buffer) -> 3 blocks/CU resident
//     (was 2 at 64 KB): cross-block TLP covers the per-block barrier convoys
//     that capped the 2-phase structure (per-step components ran serialized).
//   - next K-tile is loaded global->REGISTERS at the top of the iteration, so
//     ~L2 latency hides under the current tile's ds_read+MFMA; the LDS write
//     happens between two __syncthreads() after compute.
//   - T2 swizzle moved to the WRITE side (we control ds_write addresses now):
//     granule (row, c) is written to slot (row, c ^ (row&7)); global sources
//     are plain linear/coalesced; read side byte-identical to the proven code.
//   - no inline asm: all ordering via __syncthreads() + register data deps.
// XCD-aware bijective block swizzle (nwg % 8 == 0 for all launches) keeps each
// A/B panel resident in one XCD's L2 (FETCH_SIZE 43 MB, verified).
// EPI 0: outb = bf16((acc+bias) * (col<384 ? SCALE : 1))            (qkv, q pre-scaled)
// EPI 1: scatter window-reverse+unshift; outf[dst] = resid[dst]+acc+bias  (proj)
// EPI 2: outb = bf16(gelu(acc + bias))                              (fc1)
// EPI 3: outf[row] = resid[row] + acc + bias                        (fc2 -> d_out)
template <int EPI>
__global__ __launch_bounds__(256, 3)
void gemm_bt(const bf16* __restrict__ A, const bf16* __restrict__ Bt,
             const float* __restrict__ bias, int N, int K,
             bf16* __restrict__ outb, float* __restrict__ outf,
             const float* __restrict__ resid) {
    __shared__ bf16 As[128 * 64];
    __shared__ bf16 Bs[128 * 64];
    const int tid  = threadIdx.x;
    const int lane = tid & 63, wave = tid >> 6;
    const int quad = lane >> 4, l16 = lane & 15;
    const int wm = wave >> 1, wn = wave & 1;

    // XCD swizzle: ord%8 == XCD; give each XCD a contiguous chunk of work ids.
    const int nbx = gridDim.x;
    const int nwg = nbx * (int)gridDim.y;
    const int ord = (int)blockIdx.y * nbx + (int)blockIdx.x;
    const int cpx = nwg >> 3;                       // nwg % 8 == 0 for all launches
    const int work = (ord & 7) * cpx + (ord >> 3);
    const int by = work / nbx;
    const int bx = work - by * nbx;
    const long m0 = (long)by * 128;
    const long n0 = (long)bx * 128;

    f32x4 acc[4][4] = {};
    const int nk = K >> 6;

    // --- per-thread staging granule: e = it*256+tid -> (row = e>>3, chunk = e&7) ---
    // global src LINEAR (coalesced); LDS dest swizzled (c ^ (row&7)).
    const bf16* aG[4];
    const bf16* bG[4];
    int wOff[4];
#pragma unroll
    for (int it = 0; it < 4; ++it) {
        int e   = it * 256 + tid;
        int row = e >> 3, c = e & 7;
        aG[it]   = A  + (size_t)(m0 + row) * K + (c << 3);
        bG[it]   = Bt + (size_t)(n0 + row) * K + (c << 3);
        wOff[it] = (row * 8 + (c ^ (row & 7))) * 8;     // swizzled elem offset
    }

    bf16x8 rA[4], rB[4];
    auto ldg = [&](int k0) {
#pragma unroll
        for (int it = 0; it < 4; ++it) {
            rA[it] = *(const bf16x8*)(aG[it] + k0);
            rB[it] = *(const bf16x8*)(bG[it] + k0);
        }
    };
    auto dsw = [&]() {
#pragma unroll
        for (int it = 0; it < 4; ++it) {
            *(bf16x8*)(As + wOff[it]) = rA[it];
            *(bf16x8*)(Bs + wOff[it]) = rB[it];
        }
    };

    ldg(0);
    dsw();                                          // reg data dep forces vmcnt
    __syncthreads();                                // tile 0 visible

    const int sxA = (l16 & 7);                      // read-side swizzle (per-lane const)
    for (int kt = 0; kt < nk; ++kt) {
        const bool more = (kt + 1 < nk);
        if (more) ldg((kt + 1) * 64);               // prefetch next tile into regs;
                                                    // latency hides under compute
#pragma unroll
        for (int kk = 0; kk < 64; kk += 32) {
            const int cs = quad + (kk >> 3);        // global chunk wanted (0..7)
            const int so = ((cs ^ sxA) << 3);       // swizzled elem offset in row
            bf16x8 af[4], bfr[4];
#pragma unroll
            for (int i = 0; i < 4; ++i)
                af[i] = *(const bf16x8*)(As + (wm * 64 + i * 16 + l16) * 64 + so);
#pragma unroll
            for (int j = 0; j < 4; ++j)
                bfr[j] = *(const bf16x8*)(Bs + (wn * 64 + j * 16 + l16) * 64 + so);
#pragma unroll
            for (int i = 0; i < 4; ++i)
#pragma unroll
                for (int j = 0; j < 4; ++j)
                    acc[i][j] = __builtin_amdgcn_mfma_f32_16x16x32_bf16(af[i], bfr[j], acc[i][j], 0, 0, 0);
        }
        if (more) {
            __syncthreads();                        // all waves done reading As/Bs
            dsw();                                  // write next tile (swizzled)
            __syncthreads();                        // next tile visible
        }
    }

#pragma unroll
    for (int i = 0; i < 4; ++i) {
        const long mbase = m0 + wm * 64 + i * 16 + quad * 4;
#pragma unroll
        for (int j = 0; j < 4; ++j) {
            const int col = (int)n0 + wn * 64 + j * 16 + l16;
            const float bv = bias[col];
            f32x4 r = acc[i][j];
#pragma unroll
            for (int t = 0; t < 4; ++t) {
                const long m = mbase + t;
                float val = r[t] + bv;
                if constexpr (EPI == 0) {
                    float sc = (col < 384) ? SCALEv : 1.0f;
                    outb[(size_t)m * N + col] = (bf16)(val * sc);
                } else if constexpr (EPI == 1) {
                    int w  = (int)(m / 49), n = (int)(m - (long)w * 49);
                    int b  = w >> 6, win = w & 63;
                    int hb = win >> 3, wb = win & 7;
                    int ii = n / 7, jj = n - ii * 7;
                    int hh = hb * 7 + ii + 3; if (hh >= 56) hh -= 56;
                    int ww = wb * 7 + jj + 3; if (ww >= 56) ww -= 56;
                    size_t dst = ((size_t)b * 3136 + hh * 56 + ww) * 384 + col;
                    outf[dst] = resid[dst] + val;
                } else if constexpr (EPI == 2) {
                    float g = 0.5f * val * (1.0f + erff(val * 0.70710678118654752f));
                    outb[(size_t)m * N + col] = (bf16)g;
                } else {
                    size_t oo = (size_t)m * N + col;
                    outf[oo] = resid[oo] + val;
                }
            }
        }
    }
}

// ---------------- launch ----------------
extern "C" void kernel_launch(void* const* d_in, const int* in_sizes, int n_in,
                              void* d_out, int out_size, void* d_ws, size_t ws_size,
                              hipStream_t stream) {
    const float* x     = (const float*)d_in[0];
    const float* n1g   = (const float*)d_in[1];
    const float* n1b   = (const float*)d_in[2];
    const float* qkvw  = (const float*)d_in[3];
    const float* qkvb  = (const float*)d_in[4];
    const float* btab  = (const float*)d_in[5];
    const float* projw = (const float*)d_in[6];
    const float* projb = (const float*)d_in[7];
    const float* n2g   = (const float*)d_in[8];
    const float* n2b   = (const float*)d_in[9];
    const float* fc1w  = (const float*)d_in[10];
    const float* fc1b  = (const float*)d_in[11];
    const float* fc2w  = (const float*)d_in[12];
    const float* fc2b  = (const float*)d_in[13];
    float* out = (float*)d_out;

    char* ws = (char*)d_ws;
    size_t off = 0;
    auto take = [&](size_t bytes) {
        char* p = ws + off;
        off += (bytes + 255) & ~(size_t)255;
        return p;
    };
    bf16* qkv_wt  = (bf16*)take((size_t)1152 * 384 * 2);
    bf16* proj_wt = (bf16*)take((size_t)384 * 384 * 2);
    bf16* fc1_wt  = (bf16*)take((size_t)1536 * 384 * 2);
    bf16* fc2_wt  = (bf16*)take((size_t)384 * 1536 * 2);
    float* bmt    = (float*)take((size_t)4 * 12 * 64 * 64 * 4);
    bf16* qkv_buf = (bf16*)take((size_t)Mv * 1152 * 2);   // 231 MB
    bf16* o_buf   = (bf16*)take((size_t)Mv * 384 * 2);    // 77 MB
    bf16* hw_buf  = (bf16*)take((size_t)Mv * 384 * 2);    // 77 MB, later reused as x1n
    float* x1     = (float*)take((size_t)Mv * 384 * 4);   // 154 MB
    bf16* g_buf   = qkv_buf;   // fc1 output spans dead qkv+o regions
    bf16* x1n     = hw_buf;    // hw dead after qkv GEMM

    wt_kernel<<<(384 * 1152 + 255) / 256, 256, 0, stream>>>(qkvw,  qkv_wt,  384, 1152);
    wt_kernel<<<(384 * 384  + 255) / 256, 256, 0, stream>>>(projw, proj_wt, 384, 384);
    wt_kernel<<<(384 * 1536 + 255) / 256, 256, 0, stream>>>(fc1w,  fc1_wt,  384, 1536);
    wt_kernel<<<(1536 * 384 + 255) / 256, 256, 0, stream>>>(fc2w,  fc2_wt,  1536, 384);
    bm_kernel<<<dim3(4, 12), 256, 0, stream>>>(btab, bmt);
    ln_kernel<0><<<Mv / 4, 256, 0, stream>>>(x, n1g, n1b, hw_buf);
    gemm_bt<0><<<dim3(1152 / 128, Mv / 128), 256, 0, stream>>>(
        hw_buf, qkv_wt, qkvb, 1152, 384, qkv_buf, nullptr, nullptr);
    attn_kernel<<<dim3(2048, 12), 64, 0, stream>>>(qkv_buf, bmt, o_buf);
    gemm_bt<1><<<dim3(384 / 128, Mv / 128), 256, 0, stream>>>(
        o_buf, proj_wt, projb, 384, 384, nullptr, x1, x);
    ln_kernel<1><<<Mv / 4, 256, 0, stream>>>(x1, n2g, n2b, x1n);
    gemm_bt<2><<<dim3(1536 / 128, Mv / 128), 256, 0, stream>>>(
        x1n, fc1_wt, fc1b, 1536, 384, g_buf, nullptr, nullptr);
    gemm_bt<3><<<dim3(384 / 128, Mv / 128), 256, 0, stream>>>(
        g_buf, fc2_wt, fc2b, 384, 1536, nullptr, out, x1);
}

// Round 7
// 1123.702 us; speedup vs baseline: 1.0093x; 1.0093x over previous
//
#include <hip/hip_runtime.h>
#include <hip/hip_bf16.h>
#include <cstdint>
#include <cstddef>

// ---------------- problem constants ----------------
static constexpr int Bv  = 32;
static constexpr int Cv  = 384;
static constexpr int Nv  = 49;    // tokens per window
static constexpr int Mv  = 32 * 64 * 49;   // 100352 token-rows
static constexpr float SCALEv = 0.17677669529663687f;  // 32^-0.5

using bf16 = __hip_bfloat16;
typedef __bf16 bf16x8 __attribute__((ext_vector_type(8)));
typedef float  f32x4  __attribute__((ext_vector_type(4)));

// ---------------- weight transpose + bf16 cast: wt[n*K+k] = w[k*N+n] ----------------
__global__ __launch_bounds__(256)
void wt_kernel(const float* __restrict__ w, bf16* __restrict__ wt, int K, int N) {
    int idx = blockIdx.x * 256 + threadIdx.x;
    if (idx >= K * N) return;
    int n = idx / K, k = idx - n * K;
    wt[idx] = (bf16)w[(size_t)k * N + n];
}

// ---------------- combined rel-bias + shift-mask table (TRANSPOSED: [q][k]) --------
// BMt[cls][h][q 64][k 64] f32.  cls = (hb==7)*2 + (wb==7).
// k >= 49 -> -1e30 (kills padded K columns in swapped-QK^T layout); q clamped to 48.
__global__ __launch_bounds__(256)
void bm_kernel(const float* __restrict__ btab, float* __restrict__ bmt) {
    const int cls = blockIdx.x, h = blockIdx.y;
    for (int idx = threadIdx.x; idx < 4096; idx += 256) {
        int q = idx >> 6, k = idx & 63;
        float v;
        if (k >= 49) {
            v = -1e30f;
        } else {
            int n = q < 49 ? q : 48;   // query token
            int m = k;                 // key token
            int i1 = n / 7, j1 = n - i1 * 7;
            int i2 = m / 7, j2 = m - i2 * 7;
            v = btab[((i1 - i2 + 6) * 13 + (j1 - j2 + 6)) * 12 + h];
            int lh1 = (cls & 2) ? (i1 < 4 ? 1 : 2) : 0;
            int lw1 = (cls & 1) ? (j1 < 4 ? 1 : 2) : 0;
            int lh2 = (cls & 2) ? (i2 < 4 ? 1 : 2) : 0;
            int lw2 = (cls & 1) ? (j2 < 4 ? 1 : 2) : 0;
            if ((lh1 * 3 + lw1) != (lh2 * 3 + lw2)) v += -100.f;
        }
        bmt[((size_t)(cls * 12 + h) * 64 + q) * 64 + k] = v;
    }
}

// ---------------- LayerNorm (one wave per 384-ch row) ----------------
template <int MODE>
__global__ __launch_bounds__(256)
void ln_kernel(const float* __restrict__ src, const float* __restrict__ gam,
               const float* __restrict__ bet, bf16* __restrict__ dst) {
    const int wave = threadIdx.x >> 6, lane = threadIdx.x & 63;
    const int r = blockIdx.x * 4 + wave;             // output row
    size_t srow;
    if (MODE == 0) {
        int w  = r / 49, n = r - w * 49;
        int b  = w >> 6, win = w & 63;
        int hb = win >> 3, wb = win & 7;
        int ii = n / 7, jj = n - ii * 7;
        int hh = hb * 7 + ii + 3; if (hh >= 56) hh -= 56;   // shifted -> source row
        int ww = wb * 7 + jj + 3; if (ww >= 56) ww -= 56;
        srow = (size_t)b * 3136 + hh * 56 + ww;
    } else {
        srow = (size_t)r;
    }
    const float* p = src + srow * 384;
    float vals[6];
    float s = 0.f, s2 = 0.f;
#pragma unroll
    for (int t = 0; t < 6; ++t) {
        float v = p[t * 64 + lane];
        vals[t] = v; s += v; s2 += v * v;
    }
#pragma unroll
    for (int o = 32; o > 0; o >>= 1) {
        s  += __shfl_xor(s,  o, 64);
        s2 += __shfl_xor(s2, o, 64);
    }
    const float mu  = s * (1.f / 384.f);
    const float var = s2 * (1.f / 384.f) - mu * mu;
    const float rs  = rsqrtf(var + 1e-5f);
    bf16* q = dst + (size_t)r * 384;
#pragma unroll
    for (int t = 0; t < 6; ++t) {
        int e = t * 64 + lane;
        q[e] = (bf16)((vals[t] - mu) * rs * gam[e] + bet[e]);
    }
}

// ---------------- MFMA windowed attention: 4 waves per (window, head) --------------
// q-split across waves: wave wv owns q-block wv (q = 16*wv + l16 columns of the
// swapped S^T).  Per wave: 4 QK^T MFMAs + single-block in-register softmax +
// 2 PV MFMAs — 4x shorter serial chain than the 1-wave version, and ~16+ waves/CU
// instead of 11 (the 1-wave layout was LDS-capped at 2.75 waves/SIMD with one
// long dependent chain each: the real attn bottleneck, per round-6's null).
// K fragments are loaded by all 4 waves (same CU -> L1 hits).  Ps stripes are
// written and read by the SAME wave; only Vt needs the one __syncthreads.
__global__ __launch_bounds__(256, 4)
void attn_kernel(const bf16* __restrict__ qkv, const float* __restrict__ bmt,
                 bf16* __restrict__ o) {
    const int w = blockIdx.x;          // 0..2047
    const int h = blockIdx.y;          // 0..11
    const int tid  = threadIdx.x;
    const int wv   = tid >> 6;         // wave = q-block 0..3
    const int lane = tid & 63;
    const int quad = lane >> 4, l16 = lane & 15;
    __shared__ bf16 Vt[32][72];        // V^T, cols 49..63 zeroed
    __shared__ bf16 Ps[64][72];        // P[q][k], normalized, bf16

    const size_t rowbase = (size_t)w * 49;

    // zero pad cols 49..63 (disjoint from staged cols 0..48)
    for (int idx = tid; idx < 512; idx += 256) {
        int d = idx >> 4, c = idx & 15;
        if (c) Vt[d][48 + c] = (bf16)0.f;
    }
    // stage V^T (coalesced global read, transposed LDS write), 256 threads
    for (int idx = tid; idx < 49 * 16; idx += 256) {
        int row = idx >> 4, dp = (idx & 15) << 1;
        const bf16* src = qkv + (rowbase + row) * 1152 + 768 + h * 32 + dp;
        Vt[dp][row]     = src[0];
        Vt[dp + 1][row] = src[1];
    }

    // ---- S^T = K Q^T for this wave's q-block ----
    f32x4 acc[4] = {};
    bf16x8 kf[4], qf;
#pragma unroll
    for (int i = 0; i < 4; ++i) {
        int row = 16 * i + l16; if (row > 48) row = 48;
        kf[i] = *(const bf16x8*)(qkv + (rowbase + row) * 1152 + 384 + h * 32 + quad * 8);
    }
    {
        int row = 16 * wv + l16; if (row > 48) row = 48;
        qf = *(const bf16x8*)(qkv + (rowbase + row) * 1152 + h * 32 + quad * 8);
    }
#pragma unroll
    for (int i = 0; i < 4; ++i)
        acc[i] = __builtin_amdgcn_mfma_f32_16x16x32_bf16(kf[i], qf, acc[i], 0, 0, 0);
    // acc[i][t] = S^T[k = 16i + 4*quad + t][q = 16*wv + l16]

    // ---- bias + in-register softmax for q = 16*wv + l16 ----
    const int cls = (((w & 63) >= 56) ? 2 : 0) + (((w & 7) == 7) ? 1 : 0);
    const float* bmbase = bmt + (size_t)(cls * 12 + h) * 4096;
    f32x4 bm[4];
#pragma unroll
    for (int i = 0; i < 4; ++i)
        bm[i] = *(const f32x4*)(bmbase + (16 * wv + l16) * 64 + 16 * i + quad * 4);
    float s[4][4];
    float mx = -3.0e38f;
#pragma unroll
    for (int i = 0; i < 4; ++i)
#pragma unroll
        for (int t = 0; t < 4; ++t) {
            s[i][t] = acc[i][t] + bm[i][t];
            mx = fmaxf(mx, s[i][t]);
        }
    mx = fmaxf(mx, __shfl_xor(mx, 16, 64));
    mx = fmaxf(mx, __shfl_xor(mx, 32, 64));
    float p[4][4];
    float sum = 0.f;
#pragma unroll
    for (int i = 0; i < 4; ++i)
#pragma unroll
        for (int t = 0; t < 4; ++t) {
            p[i][t] = __expf(s[i][t] - mx);
            sum += p[i][t];
        }
    sum += __shfl_xor(sum, 16, 64);
    sum += __shfl_xor(sum, 32, 64);
    const float inv = 1.f / sum;
#pragma unroll
    for (int i = 0; i < 4; ++i) {
        bf16 pk[4];
#pragma unroll
        for (int t = 0; t < 4; ++t) pk[t] = (bf16)(p[i][t] * inv);
        *(uint64_t*)(&Ps[16 * wv + l16][16 * i + 4 * quad]) = *(const uint64_t*)pk;
    }
    __syncthreads();                   // Vt staged by all waves; Ps is wave-local

    // ---- O = P V for this wave's q rows ----
    f32x4 oacc[2] = {};
#pragma unroll
    for (int ks = 0; ks < 2; ++ks) {
        bf16x8 pa = *(const bf16x8*)(&Ps[16 * wv + l16][32 * ks + quad * 8]);
#pragma unroll
        for (int jn = 0; jn < 2; ++jn) {
            bf16x8 vb = *(const bf16x8*)(&Vt[16 * jn + l16][32 * ks + quad * 8]);
            oacc[jn] = __builtin_amdgcn_mfma_f32_16x16x32_bf16(pa, vb, oacc[jn], 0, 0, 0);
        }
    }

    // ---- store valid rows (P already normalized) ----
    const int nbase = 16 * wv + quad * 4;
#pragma unroll
    for (int t = 0; t < 4; ++t) {
        int n = nbase + t;
        if (n < 49) {
            bf16* dst = o + (rowbase + n) * 384 + h * 32;
            dst[l16]      = (bf16)(oacc[0][t]);
            dst[16 + l16] = (bf16)(oacc[1][t]);
        }
    }
}

// ---------------- bf16 MFMA GEMM, C = A[M,K] @ Bt[N,K]^T ---------------------------
// REG-PREFETCH single-buffer structure (T14):
//   - LDS halved to 32 KB (single As/Bs buffer) -> 3 blocks/CU resident
//     (was 2 at 64 KB): cross-block TLP covers the per-block barrier convoys
//     that capped the 2-phase structure (per-step components ran serialized).
//   - next K-tile is loaded global->REGISTERS at the top of the iteration, so
//     ~L2 latency hides under the current tile's ds_read+MFMA; the LDS write
//     happens between two __syncthreads() after compute.
//   - T2 swizzle moved to the WRITE side (we control ds_write addresses now):
//     granule (row, c) is written to slot (row, c ^ (row&7)); global sources
//     are plain linear/coalesced; read side byte-identical to the proven code.
//   - no inline asm: all ordering via __syncthreads() + register data deps.
// XCD-aware bijective block swizzle (nwg % 8 == 0 for all launches) keeps each
// A/B panel resident in one XCD's L2 (FETCH_SIZE 43 MB, verified).
// EPI 0: outb = bf16((acc+bias) * (col<384 ? SCALE : 1))            (qkv, q pre-scaled)
// EPI 1: scatter window-reverse+unshift; outf[dst] = resid[dst]+acc+bias  (proj)
// EPI 2: outb = bf16(gelu(acc + bias))                              (fc1)
// EPI 3: outf[row] = resid[row] + acc + bias                        (fc2 -> d_out)
template <int EPI>
__global__ __launch_bounds__(256, 3)
void gemm_bt(const bf16* __restrict__ A, const bf16* __restrict__ Bt,
             const float* __restrict__ bias, int N, int K,
             bf16* __restrict__ outb, float* __restrict__ outf,
             const float* __restrict__ resid) {
    __shared__ bf16 As[128 * 64];
    __shared__ bf16 Bs[128 * 64];
    const int tid  = threadIdx.x;
    const int lane = tid & 63, wave = tid >> 6;
    const int quad = lane >> 4, l16 = lane & 15;
    const int wm = wave >> 1, wn = wave & 1;

    // XCD swizzle: ord%8 == XCD; give each XCD a contiguous chunk of work ids.
    const int nbx = gridDim.x;
    const int nwg = nbx * (int)gridDim.y;
    const int ord = (int)blockIdx.y * nbx + (int)blockIdx.x;
    const int cpx = nwg >> 3;                       // nwg % 8 == 0 for all launches
    const int work = (ord & 7) * cpx + (ord >> 3);
    const int by = work / nbx;
    const int bx = work - by * nbx;
    const long m0 = (long)by * 128;
    const long n0 = (long)bx * 128;

    f32x4 acc[4][4] = {};
    const int nk = K >> 6;

    // --- per-thread staging granule: e = it*256+tid -> (row = e>>3, chunk = e&7) ---
    // global src LINEAR (coalesced); LDS dest swizzled (c ^ (row&7)).
    const bf16* aG[4];
    const bf16* bG[4];
    int wOff[4];
#pragma unroll
    for (int it = 0; it < 4; ++it) {
        int e   = it * 256 + tid;
        int row = e >> 3, c = e & 7;
        aG[it]   = A  + (size_t)(m0 + row) * K + (c << 3);
        bG[it]   = Bt + (size_t)(n0 + row) * K + (c << 3);
        wOff[it] = (row * 8 + (c ^ (row & 7))) * 8;     // swizzled elem offset
    }

    bf16x8 rA[4], rB[4];
    auto ldg = [&](int k0) {
#pragma unroll
        for (int it = 0; it < 4; ++it) {
            rA[it] = *(const bf16x8*)(aG[it] + k0);
            rB[it] = *(const bf16x8*)(bG[it] + k0);
        }
    };
    auto dsw = [&]() {
#pragma unroll
        for (int it = 0; it < 4; ++it) {
            *(bf16x8*)(As + wOff[it]) = rA[it];
            *(bf16x8*)(Bs + wOff[it]) = rB[it];
        }
    };

    ldg(0);
    dsw();                                          // reg data dep forces vmcnt
    __syncthreads();                                // tile 0 visible

    const int sxA = (l16 & 7);                      // read-side swizzle (per-lane const)
    for (int kt = 0; kt < nk; ++kt) {
        const bool more = (kt + 1 < nk);
        if (more) ldg((kt + 1) * 64);               // prefetch next tile into regs;
                                                    // latency hides under compute
#pragma unroll
        for (int kk = 0; kk < 64; kk += 32) {
            const int cs = quad + (kk >> 3);        // global chunk wanted (0..7)
            const int so = ((cs ^ sxA) << 3);       // swizzled elem offset in row
            bf16x8 af[4], bfr[4];
#pragma unroll
            for (int i = 0; i < 4; ++i)
                af[i] = *(const bf16x8*)(As + (wm * 64 + i * 16 + l16) * 64 + so);
#pragma unroll
            for (int j = 0; j < 4; ++j)
                bfr[j] = *(const bf16x8*)(Bs + (wn * 64 + j * 16 + l16) * 64 + so);
#pragma unroll
            for (int i = 0; i < 4; ++i)
#pragma unroll
                for (int j = 0; j < 4; ++j)
                    acc[i][j] = __builtin_amdgcn_mfma_f32_16x16x32_bf16(af[i], bfr[j], acc[i][j], 0, 0, 0);
        }
        if (more) {
            __syncthreads();                        // all waves done reading As/Bs
            dsw();                                  // write next tile (swizzled)
            __syncthreads();                        // next tile visible
        }
    }

#pragma unroll
    for (int i = 0; i < 4; ++i) {
        const long mbase = m0 + wm * 64 + i * 16 + quad * 4;
#pragma unroll
        for (int j = 0; j < 4; ++j) {
            const int col = (int)n0 + wn * 64 + j * 16 + l16;
            const float bv = bias[col];
            f32x4 r = acc[i][j];
#pragma unroll
            for (int t = 0; t < 4; ++t) {
                const long m = mbase + t;
                float val = r[t] + bv;
                if constexpr (EPI == 0) {
                    float sc = (col < 384) ? SCALEv : 1.0f;
                    outb[(size_t)m * N + col] = (bf16)(val * sc);
                } else if constexpr (EPI == 1) {
                    int w  = (int)(m / 49), n = (int)(m - (long)w * 49);
                    int b  = w >> 6, win = w & 63;
                    int hb = win >> 3, wb = win & 7;
                    int ii = n / 7, jj = n - ii * 7;
                    int hh = hb * 7 + ii + 3; if (hh >= 56) hh -= 56;
                    int ww = wb * 7 + jj + 3; if (ww >= 56) ww -= 56;
                    size_t dst = ((size_t)b * 3136 + hh * 56 + ww) * 384 + col;
                    outf[dst] = resid[dst] + val;
                } else if constexpr (EPI == 2) {
                    float g = 0.5f * val * (1.0f + erff(val * 0.70710678118654752f));
                    outb[(size_t)m * N + col] = (bf16)g;
                } else {
                    size_t oo = (size_t)m * N + col;
                    outf[oo] = resid[oo] + val;
                }
            }
        }
    }
}

// ---------------- launch ----------------
extern "C" void kernel_launch(void* const* d_in, const int* in_sizes, int n_in,
                              void* d_out, int out_size, void* d_ws, size_t ws_size,
                              hipStream_t stream) {
    const float* x     = (const float*)d_in[0];
    const float* n1g   = (const float*)d_in[1];
    const float* n1b   = (const float*)d_in[2];
    const float* qkvw  = (const float*)d_in[3];
    const float* qkvb  = (const float*)d_in[4];
    const float* btab  = (const float*)d_in[5];
    const float* projw = (const float*)d_in[6];
    const float* projb = (const float*)d_in[7];
    const float* n2g   = (const float*)d_in[8];
    const float* n2b   = (const float*)d_in[9];
    const float* fc1w  = (const float*)d_in[10];
    const float* fc1b  = (const float*)d_in[11];
    const float* fc2w  = (const float*)d_in[12];
    const float* fc2b  = (const float*)d_in[13];
    float* out = (float*)d_out;

    char* ws = (char*)d_ws;
    size_t off = 0;
    auto take = [&](size_t bytes) {
        char* p = ws + off;
        off += (bytes + 255) & ~(size_t)255;
        return p;
    };
    bf16* qkv_wt  = (bf16*)take((size_t)1152 * 384 * 2);
    bf16* proj_wt = (bf16*)take((size_t)384 * 384 * 2);
    bf16* fc1_wt  = (bf16*)take((size_t)1536 * 384 * 2);
    bf16* fc2_wt  = (bf16*)take((size_t)384 * 1536 * 2);
    float* bmt    = (float*)take((size_t)4 * 12 * 64 * 64 * 4);
    bf16* qkv_buf = (bf16*)take((size_t)Mv * 1152 * 2);   // 231 MB
    bf16* o_buf   = (bf16*)take((size_t)Mv * 384 * 2);    // 77 MB
    bf16* hw_buf  = (bf16*)take((size_t)Mv * 384 * 2);    // 77 MB, later reused as x1n
    float* x1     = (float*)take((size_t)Mv * 384 * 4);   // 154 MB
    bf16* g_buf   = qkv_buf;   // fc1 output spans dead qkv+o regions
    bf16* x1n     = hw_buf;    // hw dead after qkv GEMM

    wt_kernel<<<(384 * 1152 + 255) / 256, 256, 0, stream>>>(qkvw,  qkv_wt,  384, 1152);
    wt_kernel<<<(384 * 384  + 255) / 256, 256, 0, stream>>>(projw, proj_wt, 384, 384);
    wt_kernel<<<(384 * 1536 + 255) / 256, 256, 0, stream>>>(fc1w,  fc1_wt,  384, 1536);
    wt_kernel<<<(1536 * 384 + 255) / 256, 256, 0, stream>>>(fc2w,  fc2_wt,  1536, 384);
    bm_kernel<<<dim3(4, 12), 256, 0, stream>>>(btab, bmt);
    ln_kernel<0><<<Mv / 4, 256, 0, stream>>>(x, n1g, n1b, hw_buf);
    gemm_bt<0><<<dim3(1152 / 128, Mv / 128), 256, 0, stream>>>(
        hw_buf, qkv_wt, qkvb, 1152, 384, qkv_buf, nullptr, nullptr);
    attn_kernel<<<dim3(2048, 12), 256, 0, stream>>>(qkv_buf, bmt, o_buf);
    gemm_bt<1><<<dim3(384 / 128, Mv / 128), 256, 0, stream>>>(
        o_buf, proj_wt, projb, 384, 384, nullptr, x1, x);
    ln_kernel<1><<<Mv / 4, 256, 0, stream>>>(x1, n2g, n2b, x1n);
    gemm_bt<2><<<dim3(1536 / 128, Mv / 128), 256, 0, stream>>>(
        x1n, fc1_wt, fc1b, 1536, 384, g_buf, nullptr, nullptr);
    gemm_bt<3><<<dim3(384 / 128, Mv / 128), 256, 0, stream>>>(
        g_buf, fc2_wt, fc2b, 384, 1536, nullptr, out, x1);
}